// Round 6
// baseline (622.465 us; speedup 1.0000x reference)
//
#include <hip/hip_runtime.h>
#include <stdint.h>

#define B_   32
#define T_   2048
#define V_   50000
#define WD_  300
#define P_   150
#define KP   320       // K padded (300 -> 320)
#define MP   2112      // trans row stride in elements
#define MB2  2176      // diagsB padded rows (17 tiles of 128)
#define NPAD2 50176    // V padded to 256-multiple
#define VT2  196       // NPAD2/256
#define MT_  17
#define NWG2 3332      // VT2*MT_
#define NEGC (-1.0e30f)

// workspace layouts (bytes)
// big mode (CHUNK=32):  embT@0 (32,112,640) | diagsB@32,112,640 (1,392,640) |
//                       chunkout@0 (54,067,200, aliases embT+diagsB after gemm) |
//                       trans@54,067,200 (211,200,000) -> need 265,267,200
// small mode (CHUNK=64): trans@33,505,280 -> need 244,705,280; chunkout@0 (27,033,600)
#define WS_DIAGSB      32112640u
#define WS_TRANS_BIG   54067200u
#define WS_TRANS_SMALL 33505280u
#define WS_NEED_BIG    265267200u
#define WS_NEED_SMALL  244705280u

typedef __attribute__((ext_vector_type(8))) short bf16x8;
typedef __attribute__((ext_vector_type(4))) float f32x4;

#define GLOAD_LDS16(gp, lp) __builtin_amdgcn_global_load_lds( \
    (__attribute__((address_space(1))) void*)(gp), \
    (__attribute__((address_space(3))) void*)(lp), 16, 0, 0)

__device__ __forceinline__ unsigned short f2bf(float f){
  unsigned u = __builtin_bit_cast(unsigned, f);
  u = u + 0x7fffu + ((u >> 16) & 1u);   // RNE
  return (unsigned short)(u >> 16);
}
__device__ __forceinline__ float bf_lo(unsigned u){ return __builtin_bit_cast(float, u << 16); }
__device__ __forceinline__ float bf_hi(unsigned u){ return __builtin_bit_cast(float, u & 0xffff0000u); }

// ---------------- K0a: emb [300][50000] f32 -> embT bf16 [NPAD2][KP] (transposed, zero-padded)
__global__ __launch_bounds__(256) void k_transpose_emb(const float* __restrict__ emb,
                                                       unsigned short* __restrict__ embT){
  __shared__ float tile[32][65];
  int v0 = blockIdx.x * 64, k0 = blockIdx.y * 32;
  int tid = threadIdx.x;
  #pragma unroll
  for (int it = 0; it < 8; ++it){
    int idx = it * 256 + tid;
    int kk = idx >> 6, vv = idx & 63;
    int k = k0 + kk, v = v0 + vv;
    float val = 0.f;
    if (k < WD_ && v < V_) val = emb[(size_t)k * V_ + v];
    tile[kk][vv] = val;
  }
  __syncthreads();
  int row = tid >> 2, c = tid & 3;     // row: v within tile, c: k-quad (8 bf16)
  unsigned short e[8];
  #pragma unroll
  for (int i = 0; i < 8; ++i) e[i] = f2bf(tile[c*8 + i][row]);
  uint4 pk;
  pk.x = (unsigned)e[0] | ((unsigned)e[1] << 16);
  pk.y = (unsigned)e[2] | ((unsigned)e[3] << 16);
  pk.z = (unsigned)e[4] | ((unsigned)e[5] << 16);
  pk.w = (unsigned)e[6] | ((unsigned)e[7] << 16);
  *(uint4*)&embT[(size_t)(v0 + row) * KP + k0 + c*8] = pk;
}

// ---------------- K0b: diags [2100][300] f32 -> bf16 [MB2][KP] zero-padded
__global__ __launch_bounds__(256) void k_conv_diags(const float* __restrict__ diags,
                                                    unsigned short* __restrict__ diagsB){
  int gid = blockIdx.x * 256 + threadIdx.x;   // 0 .. 2176*80-1
  int m = gid / 80;
  int k4 = (gid % 80) * 4;
  unsigned short e[4];
  #pragma unroll
  for (int i = 0; i < 4; ++i){
    int k = k4 + i;
    float v = (m < 2100 && k < WD_) ? diags[m * WD_ + k] : 0.f;
    e[i] = f2bf(v);
  }
  uint2 pk;
  pk.x = (unsigned)e[0] | ((unsigned)e[1] << 16);
  pk.y = (unsigned)e[2] | ((unsigned)e[3] << 16);
  *(uint2*)&diagsB[(size_t)m * KP + k4] = pk;
}

// ---------------- K1: trans[v][m] = sum_k embT[v][k]*diagsB[m][k] + bias[m], bf16 out
// 256x128 tile, 8 waves (4v x 2m), BK=32, double-buffered LDS (48KB -> 3 blocks/CU),
// counted vmcnt(3), pre-swizzled source slot (slot ^ ((row>>1)&3)).
__global__ __launch_bounds__(512, 6) void k_gemm(const unsigned short* __restrict__ embT,
                                                 const unsigned short* __restrict__ diagsB,
                                                 const float* __restrict__ bias,
                                                 unsigned short* __restrict__ trans){
  __shared__ char smem[49152];   // 2 x (A 16K + B 8K); epilogue bf16 [128][132] = 33792
  // XCD-bijective blockIdx swizzle (nwg = 3332 = 8*416 + 4), mt-inner
  int orig = blockIdx.x;
  int xcd = orig & 7, bidx = orig >> 3;
  int wg = (xcd < 4 ? xcd * 417 : 1668 + (xcd - 4) * 416) + bidx;
  int vt = wg / MT_, mt = wg - vt * MT_;
  int v0 = vt * 256, m0 = mt * 128;

  int tid = threadIdx.x;
  int w = tid >> 6, l = tid & 63;
  int wm = w & 1, wv = w >> 1;         // wave tile: rows wv*64.., cols wm*64..
  int lrow = l & 15, lq = l >> 4;

  f32x4 acc[4][4];
  #pragma unroll
  for (int i = 0; i < 4; ++i)
    #pragma unroll
    for (int j = 0; j < 4; ++j)
      acc[i][j] = (f32x4){0.f, 0.f, 0.f, 0.f};

  auto STAGE = [&](int buf, int kt){
    int k0 = kt * 32;
    char* bA = smem + buf * 24576;
    char* bB = bA + 16384;
    #pragma unroll
    for (int it = 0; it < 2; ++it){            // A: 256 rows x 64B
      int idx = it * 512 + tid;
      int row = idx >> 2, slot = idx & 3;
      int sc = slot ^ ((row >> 1) & 3);
      GLOAD_LDS16(&embT[(size_t)(v0 + row) * KP + k0 + sc * 8], bA + idx * 16);
    }
    {                                          // B: 128 rows x 64B
      int row = tid >> 2, slot = tid & 3;
      int sc = slot ^ ((row >> 1) & 3);
      GLOAD_LDS16(&diagsB[(size_t)(m0 + row) * KP + k0 + sc * 8], bB + tid * 16);
    }
  };

  STAGE(0, 0);
  #pragma unroll
  for (int kt = 0; kt < 10; ++kt){
    if (kt < 9){
      STAGE((kt + 1) & 1, kt + 1);
      asm volatile("s_waitcnt vmcnt(3)" ::: "memory");
    } else {
      asm volatile("s_waitcnt vmcnt(0)" ::: "memory");
    }
    __builtin_amdgcn_s_barrier();
    __builtin_amdgcn_sched_barrier(0);
    char* bA = smem + (kt & 1) * 24576;
    char* bB = bA + 16384;
    bf16x8 af[4], bg[4];
    #pragma unroll
    for (int i = 0; i < 4; ++i){
      int row = wv * 64 + i * 16 + lrow;
      af[i] = *(const bf16x8*)(bA + row * 64 + (lq ^ ((row >> 1) & 3)) * 16);
    }
    #pragma unroll
    for (int j = 0; j < 4; ++j){
      int row = wm * 64 + j * 16 + lrow;
      bg[j] = *(const bf16x8*)(bB + row * 64 + (lq ^ ((row >> 1) & 3)) * 16);
    }
    #pragma unroll
    for (int i = 0; i < 4; ++i)
      #pragma unroll
      for (int j = 0; j < 4; ++j)
        acc[i][j] = __builtin_amdgcn_mfma_f32_16x16x32_bf16(af[i], bg[j], acc[i][j], 0, 0, 0);
    __builtin_amdgcn_sched_barrier(0);
    __builtin_amdgcn_s_barrier();
  }

  // bias per thread's 4 col-groups
  float bv4[4];
  #pragma unroll
  for (int j = 0; j < 4; ++j){
    int mg = m0 + wm * 64 + j * 16 + lrow;
    bv4[j] = (mg < 2100) ? bias[mg] : 0.f;
  }
  // epilogue: two 128-row half-passes through LDS bf16 [128][132]
  unsigned short* eb = (unsigned short*)smem;
  #pragma unroll
  for (int h = 0; h < 2; ++h){
    if (h) __syncthreads();
    if ((wv >> 1) == h){
      #pragma unroll
      for (int i = 0; i < 4; ++i)
        #pragma unroll
        for (int j = 0; j < 4; ++j)
          #pragma unroll
          for (int r = 0; r < 4; ++r){
            int row = (wv & 1) * 64 + i * 16 + lq * 4 + r;
            int col = wm * 64 + j * 16 + lrow;
            eb[row * 132 + col] = f2bf(acc[i][j][r] + bv4[j]);
          }
    }
    __syncthreads();
    #pragma unroll
    for (int it = 0; it < 8; ++it){
      int idx2 = it * 512 + tid;
      int row = idx2 >> 5, chq = idx2 & 31;   // chq: 8-byte units (4 bf16)
      int vg = v0 + h * 128 + row, mg = m0 + chq * 4;
      if (vg < V_ && mg < MP){
        uint2 val = *(const uint2*)(smem + row * 264 + chq * 8);
        *(uint2*)&trans[(size_t)vg * MP + mg] = val;
      }
    }
  }
}

// ---------------- K3: chunked affine max-plus scan (templated chunk size)
// per (b, chunk, p): fold CH steps into (A cols tri-28, b 7, u 7, w 1) -> chunkout[...][44]
// whole-chunk early exit when chunk start >= doclen (identity map, skipped by combine)
template<int CH>
__global__ __launch_bounds__(192) void k_scan(const unsigned short* __restrict__ trans,
                                              const int* __restrict__ docs,
                                              const int* __restrict__ doc_lens,
                                              const float* __restrict__ epsilon,
                                              float* __restrict__ chunkout){
  constexpr int NCHT = T_ / CH;
  __shared__ int sdocs[CH];
  int b = blockIdx.x / NCHT, ch = blockIdx.x % NCHT;
  int doclen = doc_lens[b];
  int tbase = ch * CH;
  if (tbase >= doclen) return;   // fully inactive chunk: identity record, combine skips
  int tid = threadIdx.x;
  if (tid < CH) sdocs[tid] = docs[b * T_ + tbase + tid];
  __syncthreads();
  int p = tid;
  if (p >= P_) return;
  float eps_r[6];
  #pragma unroll
  for (int i = 0; i < 6; ++i) eps_r[i] = epsilon[p*6 + i];
  int endsel = p / 50;   // 0,1,2 -> end state 4,5,6

  float col[7][7], bvec[7], uvec[7], w;
  #pragma unroll
  for (int j = 0; j < 7; ++j)
    #pragma unroll
    for (int l = 0; l < 7; ++l) col[j][l] = (j == l) ? 0.f : NEGC;
  #pragma unroll
  for (int l = 0; l < 7; ++l){ bvec[l] = NEGC; uvec[l] = NEGC; }
  w = NEGC;

  const char* transB = (const char*)trans;

  auto LOADQ = [&](unsigned* q, int s){
    int idx = s < CH - 1 ? s : CH - 1;
    const unsigned* rp = (const unsigned*)(transB + (size_t)sdocs[idx] * (MP*2) + p*28);
    #pragma unroll
    for (int i = 0; i < 7; ++i) q[i] = rp[i];
  };

  auto step = [&](const unsigned* q, bool act){
    float tsf[7], tmn[6];
    tsf[0]=bf_lo(q[0]); tsf[1]=bf_hi(q[0]);
    tsf[2]=bf_lo(q[1]); tsf[3]=bf_hi(q[1]);
    tsf[4]=bf_lo(q[2]); tsf[5]=bf_hi(q[2]);
    tsf[6]=bf_lo(q[3]); tmn[0]=bf_hi(q[3]);
    tmn[1]=bf_lo(q[4]); tmn[2]=bf_hi(q[4]);
    tmn[3]=bf_lo(q[5]); tmn[4]=bf_hi(q[5]);
    tmn[5]=bf_lo(q[6]);
    // linear part: update each (triangular) column, descending l so old values are read
    #pragma unroll
    for (int j = 0; j < 7; ++j){
      #pragma unroll
      for (int l = 6; l >= 1; --l){
        if (l < j) continue;
        if (l == j){ col[j][l] = col[j][l] + tsf[l]; continue; }
        float ae;
        if (l - 1 == j) ae = col[j][l-1];
        else ae = fmaxf(col[j][l-1], col[j][l-2] + eps_r[l-2]);
        col[j][l] = fmaxf(ae + tmn[l-1], col[j][l] + tsf[l]);
      }
      if (j == 0) col[0][0] += tsf[0];
    }
    // const part: full reference map incl. restart(0) and zero_pad(-100)
    #pragma unroll
    for (int l = 6; l >= 1; --l){
      float ae;
      if (l == 1) ae = fmaxf(bvec[0], -100.0f);
      else ae = fmaxf(bvec[l-1], bvec[l-2] + eps_r[l-2]);
      bvec[l] = fmaxf(ae + tmn[l-1], bvec[l] + tsf[l]);
    }
    bvec[0] = fmaxf(0.0f, bvec[0] + tsf[0]);
    if (act){
      #pragma unroll
      for (int j = 0; j < 7; ++j){
        float c4 = (j <= 4) ? col[j][4] : NEGC;
        float c5 = (j <= 5) ? col[j][5] : NEGC;
        float c6 = col[j][6];
        float ce = (endsel == 0) ? c4 : ((endsel == 1) ? c5 : c6);
        uvec[j] = fmaxf(uvec[j], ce);
      }
      float be = (endsel == 0) ? bvec[4] : ((endsel == 1) ? bvec[5] : bvec[6]);
      w = fmaxf(w, be);
    }
  };

  unsigned q0[7], q1[7], q2[7], q3[7];
  LOADQ(q0, 0); LOADQ(q1, 1); LOADQ(q2, 2);
  for (int s = 0; s < CH; s += 4){
    LOADQ(q3, s + 3); step(q0, (tbase + s)     < doclen);
    LOADQ(q0, s + 4); step(q1, (tbase + s + 1) < doclen);
    LOADQ(q1, s + 5); step(q2, (tbase + s + 2) < doclen);
    LOADQ(q2, s + 6); step(q3, (tbase + s + 3) < doclen);
  }

  float out[44];
  int idx = 0;
  #pragma unroll
  for (int j = 0; j < 7; ++j)
    #pragma unroll
    for (int l = j; l < 7; ++l) out[idx++] = col[j][l];
  #pragma unroll
  for (int l = 0; l < 7; ++l) out[28 + l] = bvec[l];
  #pragma unroll
  for (int l = 0; l < 7; ++l) out[35 + l] = uvec[l];
  out[42] = w; out[43] = 0.f;
  float* dst = chunkout + ((size_t)(b * NCHT + ch) * P_ + p) * 44;
  #pragma unroll
  for (int i = 0; i < 11; ++i){
    float4 t2 = make_float4(out[4*i], out[4*i+1], out[4*i+2], out[4*i+3]);
    ((float4*)dst)[i] = t2;
  }
}

// ---------------- K45: per-(b,p) fold of active chunks + MLP head
__global__ __launch_bounds__(192) void k_combine_mlp(const float* __restrict__ chunkout,
                                                     const int* __restrict__ doc_lens,
                                                     const float* __restrict__ w0,
                                                     const float* __restrict__ b0,
                                                     const float* __restrict__ w1,
                                                     const float* __restrict__ b1,
                                                     float* __restrict__ out,
                                                     int nch, int chsz){
  __shared__ float ssc[P_];
  __shared__ float sh[100];
  int b = blockIdx.x, tid = threadIdx.x;
  if (tid < P_){
    int p = tid;
    int doclen = doc_lens[b];
    int nact = (doclen + chsz - 1) / chsz;
    if (nact > nch) nact = nch;
    float h[7] = {0.f, -100.f, -100.f, -100.f, -100.f, -100.f, -100.f};
    float sc = -100.f;
    for (int ch = 0; ch < nact; ++ch){
      const float* rec = chunkout + ((size_t)(b * nch + ch) * P_ + p) * 44;
      float r[44];
      #pragma unroll
      for (int i = 0; i < 11; ++i){
        float4 t = ((const float4*)rec)[i];
        r[4*i] = t.x; r[4*i+1] = t.y; r[4*i+2] = t.z; r[4*i+3] = t.w;
      }
      // score with OLD h (u . h, w)
      #pragma unroll
      for (int j = 0; j < 7; ++j) sc = fmaxf(sc, r[35 + j] + h[j]);
      sc = fmaxf(sc, r[42]);
      // h' = A (x) h  (+)  b
      constexpr int off[7] = {0, 7, 13, 18, 22, 25, 27};
      float nh[7];
      #pragma unroll
      for (int l = 0; l < 7; ++l){
        float v = r[28 + l];
        #pragma unroll
        for (int j = 0; j < 7; ++j){
          if (j <= l) v = fmaxf(v, r[off[j] + (l - j)] + h[j]);
        }
        nh[l] = v;
      }
      #pragma unroll
      for (int l = 0; l < 7; ++l) h[l] = nh[l];
    }
    ssc[p] = sc;
  }
  __syncthreads();
  if (tid < 100){
    float a = b0[tid];
    for (int pp = 0; pp < P_; ++pp) a += ssc[pp] * w0[pp * 100 + tid];
    sh[tid] = fmaxf(a, 0.f);
  }
  __syncthreads();
  if (tid < 2){
    float o = b1[tid];
    for (int j = 0; j < 100; ++j) o += sh[j] * w1[j * 2 + tid];
    out[b * 2 + tid] = o;
  }
}

extern "C" void kernel_launch(void* const* d_in, const int* in_sizes, int n_in,
                              void* d_out, int out_size, void* d_ws, size_t ws_size,
                              hipStream_t stream){
  const float* emb   = (const float*)d_in[0];   // [300][50000]
  const float* diags = (const float*)d_in[1];   // [2100][300]
  const float* bias  = (const float*)d_in[2];   // [2100]
  const float* eps   = (const float*)d_in[3];   // [150][6]
  const float* w0    = (const float*)d_in[4];   // [150][100]
  const float* b0    = (const float*)d_in[5];   // [100]
  const float* w1    = (const float*)d_in[6];   // [100][2]
  const float* b1    = (const float*)d_in[7];   // [2]
  const int* docs    = (const int*)d_in[8];     // [32][2048]
  const int* dlens   = (const int*)d_in[9];     // [32]

  if (ws_size < (size_t)WS_NEED_SMALL) return;  // all-zero output => ws too small
  bool big = ws_size >= (size_t)WS_NEED_BIG;

  char* ws = (char*)d_ws;
  unsigned short* embT   = (unsigned short*)(ws);
  unsigned short* diagsB = (unsigned short*)(ws + WS_DIAGSB);
  unsigned short* trans  = (unsigned short*)(ws + (big ? WS_TRANS_BIG : WS_TRANS_SMALL));
  float* chunkout        = (float*)(ws);        // aliases embT+diagsB (dead after k_gemm)
  float* outp = (float*)d_out;

  k_transpose_emb<<<dim3(NPAD2/64, KP/32), 256, 0, stream>>>(emb, embT);
  k_conv_diags<<<(MB2*80 + 255)/256, 256, 0, stream>>>(diags, diagsB);
  k_gemm<<<NWG2, 512, 0, stream>>>(embT, diagsB, bias, trans);
  if (big){
    k_scan<32><<<B_ * 64, 192, 0, stream>>>(trans, docs, dlens, eps, chunkout);
    k_combine_mlp<<<B_, 192, 0, stream>>>(chunkout, dlens, w0, b0, w1, b1, outp, 64, 32);
  } else {
    k_scan<64><<<B_ * 32, 192, 0, stream>>>(trans, docs, dlens, eps, chunkout);
    k_combine_mlp<<<B_, 192, 0, stream>>>(chunkout, dlens, w0, b0, w1, b1, outp, 32, 64);
  }
}

// Round 7
// 222.161 us; speedup vs baseline: 2.8019x; 2.8019x over previous
//
#include <hip/hip_runtime.h>
#include <stdint.h>

#define B_   32
#define T_   2048
#define V_   50000
#define WD_  300
#define P_   150
#define KP   320       // K padded (300 -> 320)
#define MP   2112      // trans row stride in elements
#define MB2  2176      // diagsB padded rows
#define NPAD2 50176    // V padded (transpose output rows)
#define VT_  391       // compact-row tiles of 128 (worst case 50048/128)
#define MT_  17
#define NWG  6647      // VT_*MT_
#define NEGC (-1.0e30f)

// workspace layouts (bytes)
// big (CHUNK=32):  embT@0 (32,112,640) | diagsB@32,112,640 (1,392,640) |
//                  chunkout@0 (54,067,200; aliases embT+diagsB after gemm) |
//                  trans@54,067,200 (211,200,000) | aux@265,267,200 (864,260)
// small (CHUNK=64): trans@33,505,280 | aux@244,705,280; chunkout@0 (27,033,600)
#define WS_DIAGSB      32112640u
#define WS_TRANS_BIG   54067200u
#define WS_TRANS_SMALL 33505280u
#define WS_AUX_BIG     265267200u
#define WS_AUX_SMALL   244705280u
#define AUX_BYTES      864260u
#define WS_NEED_BIG    (WS_AUX_BIG + AUX_BYTES)
#define WS_NEED_SMALL  (WS_AUX_SMALL + AUX_BYTES)

typedef __attribute__((ext_vector_type(8))) short bf16x8;
typedef __attribute__((ext_vector_type(4))) float f32x4;

#define GLOAD_LDS16(gp, lp) __builtin_amdgcn_global_load_lds( \
    (__attribute__((address_space(1))) void*)(gp), \
    (__attribute__((address_space(3))) void*)(lp), 16, 0, 0)

__device__ __forceinline__ unsigned short f2bf(float f){
  unsigned u = __builtin_bit_cast(unsigned, f);
  u = u + 0x7fffu + ((u >> 16) & 1u);   // RNE
  return (unsigned short)(u >> 16);
}
__device__ __forceinline__ float bf_lo(unsigned u){ return __builtin_bit_cast(float, u << 16); }
__device__ __forceinline__ float bf_hi(unsigned u){ return __builtin_bit_cast(float, u & 0xffff0000u); }

// ---------------- K0a: emb [300][50000] f32 -> embT bf16 [NPAD2][KP] (transposed, zero-padded)
__global__ __launch_bounds__(256) void k_transpose_emb(const float* __restrict__ emb,
                                                       unsigned short* __restrict__ embT){
  __shared__ float tile[32][65];
  int v0 = blockIdx.x * 64, k0 = blockIdx.y * 32;
  int tid = threadIdx.x;
  #pragma unroll
  for (int it = 0; it < 8; ++it){
    int idx = it * 256 + tid;
    int kk = idx >> 6, vv = idx & 63;
    int k = k0 + kk, v = v0 + vv;
    float val = 0.f;
    if (k < WD_ && v < V_) val = emb[(size_t)k * V_ + v];
    tile[kk][vv] = val;
  }
  __syncthreads();
  int row = tid >> 2, c = tid & 3;
  unsigned short e[8];
  #pragma unroll
  for (int i = 0; i < 8; ++i) e[i] = f2bf(tile[c*8 + i][row]);
  uint4 pk;
  pk.x = (unsigned)e[0] | ((unsigned)e[1] << 16);
  pk.y = (unsigned)e[2] | ((unsigned)e[3] << 16);
  pk.z = (unsigned)e[4] | ((unsigned)e[5] << 16);
  pk.w = (unsigned)e[6] | ((unsigned)e[7] << 16);
  *(uint4*)&embT[(size_t)(v0 + row) * KP + k0 + c*8] = pk;
}

// ---------------- K0b: diags [2100][300] f32 -> bf16 [MB2][KP] zero-padded
__global__ __launch_bounds__(256) void k_conv_diags(const float* __restrict__ diags,
                                                    unsigned short* __restrict__ diagsB){
  int gid = blockIdx.x * 256 + threadIdx.x;
  int m = gid / 80;
  int k4 = (gid % 80) * 4;
  unsigned short e[4];
  #pragma unroll
  for (int i = 0; i < 4; ++i){
    int k = k4 + i;
    float v = (m < 2100 && k < WD_) ? diags[m * WD_ + k] : 0.f;
    e[i] = f2bf(v);
  }
  uint2 pk;
  pk.x = (unsigned)e[0] | ((unsigned)e[1] << 16);
  pk.y = (unsigned)e[2] | ((unsigned)e[3] << 16);
  *(uint2*)&diagsB[(size_t)m * KP + k4] = pk;
}

// ---------------- vocab compaction ----------------
__global__ __launch_bounds__(256) void k_zero(int* __restrict__ used, int* __restrict__ counter){
  int i = blockIdx.x * 256 + threadIdx.x;
  if (i < NPAD2) used[i] = 0;
  if (i == 0) *counter = 0;
}
__global__ __launch_bounds__(256) void k_mark(const int* __restrict__ docs,
                                              const int* __restrict__ dlens,
                                              int* __restrict__ used){
  int i = blockIdx.x * 256 + threadIdx.x;   // 0..65535
  int b = i >> 11, t = i & 2047;
  if (t < dlens[b]) used[docs[i]] = 1;
}
__global__ __launch_bounds__(256) void k_compact(const int* __restrict__ used,
                                                 int* __restrict__ remap,
                                                 int* __restrict__ inv,
                                                 int* __restrict__ counter){
  int v = blockIdx.x * 256 + threadIdx.x;
  if (v >= V_) return;
  if (used[v]){
    int id = atomicAdd(counter, 1);
    remap[v] = id;
    inv[id] = v;
  }
}
__global__ __launch_bounds__(256) void k_docsC(const int* __restrict__ docs,
                                               const int* __restrict__ dlens,
                                               const int* __restrict__ remap,
                                               int* __restrict__ docsC){
  int i = blockIdx.x * 256 + threadIdx.x;
  int b = i >> 11, t = i & 2047;
  docsC[i] = (t < dlens[b]) ? remap[docs[i]] : 0;
}

// ---------------- K1: trans[id][m] = sum_k embT[inv[id]][k]*diagsB[m][k] + bias[m], bf16 out
// round-5 proven structure: 128x128 tile, 4 waves, BK=32, dbuf LDS, counted vmcnt(4),
// pre-swizzled source slot (slot ^ ((row>>1)&3)); A rows gathered through inv[].
__global__ __launch_bounds__(256, 4) void k_gemm(const unsigned short* __restrict__ embT,
                                                 const unsigned short* __restrict__ diagsB,
                                                 const float* __restrict__ bias,
                                                 const int* __restrict__ inv,
                                                 const int* __restrict__ nusedp,
                                                 unsigned short* __restrict__ trans){
  __shared__ char smem[33792];   // 2 x (A 8K + B 8K) = 32K; epilogue bf16 [128][132]
  int nused = *nusedp;
  // XCD-bijective blockIdx swizzle (nwg = 6647 = 8*830 + 7), mt-inner
  int orig = blockIdx.x;
  int xcd = orig & 7, bidx = orig >> 3;
  int wg = (xcd < 7 ? xcd * 831 : 5817 + (xcd - 7) * 830) + bidx;
  int vt = wg / MT_, mt = wg - vt * MT_;
  int v0 = vt * 128, m0 = mt * 128;
  if (v0 >= nused) return;

  int tid = threadIdx.x;
  int w = tid >> 6, l = tid & 63;
  int wv = w & 1, wm = w >> 1;
  int lrow = l & 15, lq = l >> 4;

  // A-row gather indices for this thread's two staged rows
  int rA0 = tid >> 2, rA1 = 64 + (tid >> 2);
  size_t ga0 = (size_t)((v0 + rA0 < nused) ? inv[v0 + rA0] : 0) * KP;
  size_t ga1 = (size_t)((v0 + rA1 < nused) ? inv[v0 + rA1] : 0) * KP;

  f32x4 acc[4][4];
  #pragma unroll
  for (int i = 0; i < 4; ++i)
    #pragma unroll
    for (int j = 0; j < 4; ++j)
      acc[i][j] = (f32x4){0.f, 0.f, 0.f, 0.f};

  auto STAGE = [&](int buf, int kt){
    int k0 = kt * 32;
    char* bA = smem + buf * 16384;
    char* bB = bA + 8192;
    int slot = tid & 3;
    {
      int idx = tid;
      int sc = slot ^ ((rA0 >> 1) & 3);
      GLOAD_LDS16(&embT[ga0 + k0 + sc * 8], bA + idx * 16);
      int row = idx >> 2;
      int scB = slot ^ ((row >> 1) & 3);
      GLOAD_LDS16(&diagsB[(size_t)(m0 + row) * KP + k0 + scB * 8], bB + idx * 16);
    }
    {
      int idx = 256 + tid;
      int sc = slot ^ ((rA1 >> 1) & 3);
      GLOAD_LDS16(&embT[ga1 + k0 + sc * 8], bA + idx * 16);
      int row = idx >> 2;
      int scB = slot ^ ((row >> 1) & 3);
      GLOAD_LDS16(&diagsB[(size_t)(m0 + row) * KP + k0 + scB * 8], bB + idx * 16);
    }
  };

  STAGE(0, 0);
  #pragma unroll
  for (int kt = 0; kt < 10; ++kt){
    if (kt < 9){
      STAGE((kt + 1) & 1, kt + 1);
      asm volatile("s_waitcnt vmcnt(4)" ::: "memory");
    } else {
      asm volatile("s_waitcnt vmcnt(0)" ::: "memory");
    }
    __builtin_amdgcn_s_barrier();
    __builtin_amdgcn_sched_barrier(0);
    char* bA = smem + (kt & 1) * 16384;
    char* bB = bA + 8192;
    bf16x8 af[4], bg[4];
    #pragma unroll
    for (int i = 0; i < 4; ++i){
      int row = wv * 64 + i * 16 + lrow;
      af[i] = *(const bf16x8*)(bA + row * 64 + (lq ^ ((row >> 1) & 3)) * 16);
    }
    #pragma unroll
    for (int j = 0; j < 4; ++j){
      int row = wm * 64 + j * 16 + lrow;
      bg[j] = *(const bf16x8*)(bB + row * 64 + (lq ^ ((row >> 1) & 3)) * 16);
    }
    #pragma unroll
    for (int i = 0; i < 4; ++i)
      #pragma unroll
      for (int j = 0; j < 4; ++j)
        acc[i][j] = __builtin_amdgcn_mfma_f32_16x16x32_bf16(af[i], bg[j], acc[i][j], 0, 0, 0);
    __builtin_amdgcn_sched_barrier(0);
    __builtin_amdgcn_s_barrier();
  }

  // bias per thread's 4 col-groups
  float bv4[4];
  #pragma unroll
  for (int j = 0; j < 4; ++j){
    int mg = m0 + wm * 64 + j * 16 + lrow;
    bv4[j] = (mg < 2100) ? bias[mg] : 0.f;
  }
  // epilogue: regs -> bf16 LDS [128][132] -> coalesced uint2 stores
  unsigned short* eb = (unsigned short*)smem;
  #pragma unroll
  for (int i = 0; i < 4; ++i)
    #pragma unroll
    for (int j = 0; j < 4; ++j)
      #pragma unroll
      for (int r = 0; r < 4; ++r){
        int row = wv * 64 + i * 16 + lq * 4 + r;
        int col = wm * 64 + j * 16 + lrow;
        eb[row * 132 + col] = f2bf(acc[i][j][r] + bv4[j]);
      }
  __syncthreads();
  #pragma unroll
  for (int it = 0; it < 16; ++it){
    int idx2 = it * 256 + tid;
    int row = idx2 >> 5, chq = idx2 & 31;   // chq: 8-byte units (4 bf16)
    int vg = v0 + row, mg = m0 + chq * 4;
    if (vg < nused && mg < MP){
      uint2 val = *(const uint2*)(smem + row * 264 + chq * 8);
      *(uint2*)&trans[(size_t)vg * MP + mg] = val;
    }
  }
}

// ---------------- K3: chunked affine max-plus scan (templated chunk size)
template<int CH>
__global__ __launch_bounds__(192) void k_scan(const unsigned short* __restrict__ trans,
                                              const int* __restrict__ docsC,
                                              const int* __restrict__ doc_lens,
                                              const float* __restrict__ epsilon,
                                              float* __restrict__ chunkout){
  constexpr int NCHT = T_ / CH;
  __shared__ int sdocs[CH];
  int b = blockIdx.x / NCHT, ch = blockIdx.x % NCHT;
  int doclen = doc_lens[b];
  int tbase = ch * CH;
  if (tbase >= doclen) return;   // fully inactive chunk: combine skips it
  int tid = threadIdx.x;
  if (tid < CH) sdocs[tid] = docsC[b * T_ + tbase + tid];
  __syncthreads();
  int p = tid;
  if (p >= P_) return;
  float eps_r[6];
  #pragma unroll
  for (int i = 0; i < 6; ++i) eps_r[i] = epsilon[p*6 + i];
  int endsel = p / 50;

  float col[7][7], bvec[7], uvec[7], w;
  #pragma unroll
  for (int j = 0; j < 7; ++j)
    #pragma unroll
    for (int l = 0; l < 7; ++l) col[j][l] = (j == l) ? 0.f : NEGC;
  #pragma unroll
  for (int l = 0; l < 7; ++l){ bvec[l] = NEGC; uvec[l] = NEGC; }
  w = NEGC;

  const char* transB = (const char*)trans;

  auto LOADQ = [&](unsigned* q, int s){
    int idx = s < CH - 1 ? s : CH - 1;
    const unsigned* rp = (const unsigned*)(transB + (size_t)sdocs[idx] * (MP*2) + p*28);
    #pragma unroll
    for (int i = 0; i < 7; ++i) q[i] = rp[i];
  };

  auto step = [&](const unsigned* q, bool act){
    float tsf[7], tmn[6];
    tsf[0]=bf_lo(q[0]); tsf[1]=bf_hi(q[0]);
    tsf[2]=bf_lo(q[1]); tsf[3]=bf_hi(q[1]);
    tsf[4]=bf_lo(q[2]); tsf[5]=bf_hi(q[2]);
    tsf[6]=bf_lo(q[3]); tmn[0]=bf_hi(q[3]);
    tmn[1]=bf_lo(q[4]); tmn[2]=bf_hi(q[4]);
    tmn[3]=bf_lo(q[5]); tmn[4]=bf_hi(q[5]);
    tmn[5]=bf_lo(q[6]);
    #pragma unroll
    for (int j = 0; j < 7; ++j){
      #pragma unroll
      for (int l = 6; l >= 1; --l){
        if (l < j) continue;
        if (l == j){ col[j][l] = col[j][l] + tsf[l]; continue; }
        float ae;
        if (l - 1 == j) ae = col[j][l-1];
        else ae = fmaxf(col[j][l-1], col[j][l-2] + eps_r[l-2]);
        col[j][l] = fmaxf(ae + tmn[l-1], col[j][l] + tsf[l]);
      }
      if (j == 0) col[0][0] += tsf[0];
    }
    #pragma unroll
    for (int l = 6; l >= 1; --l){
      float ae;
      if (l == 1) ae = fmaxf(bvec[0], -100.0f);
      else ae = fmaxf(bvec[l-1], bvec[l-2] + eps_r[l-2]);
      bvec[l] = fmaxf(ae + tmn[l-1], bvec[l] + tsf[l]);
    }
    bvec[0] = fmaxf(0.0f, bvec[0] + tsf[0]);
    if (act){
      #pragma unroll
      for (int j = 0; j < 7; ++j){
        float c4 = (j <= 4) ? col[j][4] : NEGC;
        float c5 = (j <= 5) ? col[j][5] : NEGC;
        float c6 = col[j][6];
        float ce = (endsel == 0) ? c4 : ((endsel == 1) ? c5 : c6);
        uvec[j] = fmaxf(uvec[j], ce);
      }
      float be = (endsel == 0) ? bvec[4] : ((endsel == 1) ? bvec[5] : bvec[6]);
      w = fmaxf(w, be);
    }
  };

  unsigned q0[7], q1[7], q2[7], q3[7];
  LOADQ(q0, 0); LOADQ(q1, 1); LOADQ(q2, 2);
  for (int s = 0; s < CH; s += 4){
    LOADQ(q3, s + 3); step(q0, (tbase + s)     < doclen);
    LOADQ(q0, s + 4); step(q1, (tbase + s + 1) < doclen);
    LOADQ(q1, s + 5); step(q2, (tbase + s + 2) < doclen);
    LOADQ(q2, s + 6); step(q3, (tbase + s + 3) < doclen);
  }

  float out[44];
  int idx = 0;
  #pragma unroll
  for (int j = 0; j < 7; ++j)
    #pragma unroll
    for (int l = j; l < 7; ++l) out[idx++] = col[j][l];
  #pragma unroll
  for (int l = 0; l < 7; ++l) out[28 + l] = bvec[l];
  #pragma unroll
  for (int l = 0; l < 7; ++l) out[35 + l] = uvec[l];
  out[42] = w; out[43] = 0.f;
  float* dst = chunkout + ((size_t)(b * NCHT + ch) * P_ + p) * 44;
  #pragma unroll
  for (int i = 0; i < 11; ++i){
    float4 t2 = make_float4(out[4*i], out[4*i+1], out[4*i+2], out[4*i+3]);
    ((float4*)dst)[i] = t2;
  }
}

// ---------------- K45: per-(b,p) fold of active chunks + MLP head
__global__ __launch_bounds__(192) void k_combine_mlp(const float* __restrict__ chunkout,
                                                     const int* __restrict__ doc_lens,
                                                     const float* __restrict__ w0,
                                                     const float* __restrict__ b0,
                                                     const float* __restrict__ w1,
                                                     const float* __restrict__ b1,
                                                     float* __restrict__ out,
                                                     int nch, int chsz){
  __shared__ float ssc[P_];
  __shared__ float sh[100];
  int b = blockIdx.x, tid = threadIdx.x;
  if (tid < P_){
    int p = tid;
    int doclen = doc_lens[b];
    int nact = (doclen + chsz - 1) / chsz;
    if (nact > nch) nact = nch;
    float h[7] = {0.f, -100.f, -100.f, -100.f, -100.f, -100.f, -100.f};
    float sc = -100.f;
    for (int ch = 0; ch < nact; ++ch){
      const float* rec = chunkout + ((size_t)(b * nch + ch) * P_ + p) * 44;
      float r[44];
      #pragma unroll
      for (int i = 0; i < 11; ++i){
        float4 t = ((const float4*)rec)[i];
        r[4*i] = t.x; r[4*i+1] = t.y; r[4*i+2] = t.z; r[4*i+3] = t.w;
      }
      #pragma unroll
      for (int j = 0; j < 7; ++j) sc = fmaxf(sc, r[35 + j] + h[j]);
      sc = fmaxf(sc, r[42]);
      constexpr int off[7] = {0, 7, 13, 18, 22, 25, 27};
      float nh[7];
      #pragma unroll
      for (int l = 0; l < 7; ++l){
        float v = r[28 + l];
        #pragma unroll
        for (int j = 0; j < 7; ++j){
          if (j <= l) v = fmaxf(v, r[off[j] + (l - j)] + h[j]);
        }
        nh[l] = v;
      }
      #pragma unroll
      for (int l = 0; l < 7; ++l) h[l] = nh[l];
    }
    ssc[p] = sc;
  }
  __syncthreads();
  if (tid < 100){
    float a = b0[tid];
    for (int pp = 0; pp < P_; ++pp) a += ssc[pp] * w0[pp * 100 + tid];
    sh[tid] = fmaxf(a, 0.f);
  }
  __syncthreads();
  if (tid < 2){
    float o = b1[tid];
    for (int j = 0; j < 100; ++j) o += sh[j] * w1[j * 2 + tid];
    out[b * 2 + tid] = o;
  }
}

extern "C" void kernel_launch(void* const* d_in, const int* in_sizes, int n_in,
                              void* d_out, int out_size, void* d_ws, size_t ws_size,
                              hipStream_t stream){
  const float* emb   = (const float*)d_in[0];
  const float* diags = (const float*)d_in[1];
  const float* bias  = (const float*)d_in[2];
  const float* eps   = (const float*)d_in[3];
  const float* w0    = (const float*)d_in[4];
  const float* b0    = (const float*)d_in[5];
  const float* w1    = (const float*)d_in[6];
  const float* b1    = (const float*)d_in[7];
  const int* docs    = (const int*)d_in[8];
  const int* dlens   = (const int*)d_in[9];

  if (ws_size < (size_t)WS_NEED_SMALL) return;  // all-zero output => ws too small
  bool big = ws_size >= (size_t)WS_NEED_BIG;

  char* ws = (char*)d_ws;
  unsigned short* embT   = (unsigned short*)(ws);
  unsigned short* diagsB = (unsigned short*)(ws + WS_DIAGSB);
  unsigned short* trans  = (unsigned short*)(ws + (big ? WS_TRANS_BIG : WS_TRANS_SMALL));
  char* aux              = ws + (big ? WS_AUX_BIG : WS_AUX_SMALL);
  int* used    = (int*)(aux);                 // 50176
  int* remap   = (int*)(aux + 200704u);       // 50176
  int* inv     = (int*)(aux + 401408u);       // 50176
  int* docsC   = (int*)(aux + 602112u);       // 65536
  int* counter = (int*)(aux + 864256u);       // 1
  float* chunkout = (float*)(ws);             // aliases embT+diagsB (dead after gemm)
  float* outp = (float*)d_out;

  k_transpose_emb<<<dim3(NPAD2/64, KP/32), 256, 0, stream>>>(emb, embT);
  k_conv_diags<<<(MB2*80 + 255)/256, 256, 0, stream>>>(diags, diagsB);
  k_zero<<<NPAD2/256, 256, 0, stream>>>(used, counter);
  k_mark<<<B_*T_/256, 256, 0, stream>>>(docs, dlens, used);
  k_compact<<<(V_ + 255)/256, 256, 0, stream>>>(used, remap, inv, counter);
  k_docsC<<<B_*T_/256, 256, 0, stream>>>(docs, dlens, remap, docsC);
  k_gemm<<<NWG, 256, 0, stream>>>(embT, diagsB, bias, inv, counter, trans);
  if (big){
    k_scan<32><<<B_ * 64, 192, 0, stream>>>(trans, docsC, dlens, eps, chunkout);
    k_combine_mlp<<<B_, 192, 0, stream>>>(chunkout, dlens, w0, b0, w1, b1, outp, 64, 32);
  } else {
    k_scan<64><<<B_ * 32, 192, 0, stream>>>(trans, docsC, dlens, eps, chunkout);
    k_combine_mlp<<<B_, 192, 0, stream>>>(chunkout, dlens, w0, b0, w1, b1, outp, 32, 64);
  }
}

// Round 8
// 196.912 us; speedup vs baseline: 3.1611x; 1.1282x over previous
//
#include <hip/hip_runtime.h>
#include <stdint.h>

#define B_   32
#define T_   2048
#define V_   50000
#define WD_  300
#define P_   150
#define KP   320       // K padded (300 -> 320)
#define MP   2112      // trans row stride in elements
#define MB2  2176      // diagsB padded rows
#define NPAD2 50176    // V padded (transpose output rows)
#define VT_  391       // compact-row tiles of 128 (worst case 50048/128)
#define MT_  17
#define NWG  6647      // VT_*MT_
#define NEGC (-1.0e30f)

// workspace layouts (bytes)
// big (CHUNK=32):  embT@0 (32,112,640) | diagsB@32,112,640 (1,392,640) |
//                  chunkout@0 (54,067,200; aliases embT+diagsB after gemm) |
//                  trans@54,067,200 (211,200,000) | aux@265,267,200 (864,260)
// small (CHUNK=64): trans@33,505,280 | aux@244,705,280; chunkout@0 (27,033,600)
#define WS_DIAGSB      32112640u
#define WS_TRANS_BIG   54067200u
#define WS_TRANS_SMALL 33505280u
#define WS_AUX_BIG     265267200u
#define WS_AUX_SMALL   244705280u
#define AUX_BYTES      864260u
#define WS_NEED_BIG    (WS_AUX_BIG + AUX_BYTES)
#define WS_NEED_SMALL  (WS_AUX_SMALL + AUX_BYTES)

typedef __attribute__((ext_vector_type(8))) short bf16x8;
typedef __attribute__((ext_vector_type(4))) float f32x4;

#define GLOAD_LDS16(gp, lp) __builtin_amdgcn_global_load_lds( \
    (__attribute__((address_space(1))) void*)(gp), \
    (__attribute__((address_space(3))) void*)(lp), 16, 0, 0)

__device__ __forceinline__ unsigned short f2bf(float f){
  unsigned u = __builtin_bit_cast(unsigned, f);
  u = u + 0x7fffu + ((u >> 16) & 1u);   // RNE
  return (unsigned short)(u >> 16);
}
__device__ __forceinline__ float bf_lo(unsigned u){ return __builtin_bit_cast(float, u << 16); }
__device__ __forceinline__ float bf_hi(unsigned u){ return __builtin_bit_cast(float, u & 0xffff0000u); }

// ---------------- K0a: emb [300][50000] f32 -> embT bf16 [NPAD2][KP] (transposed, zero-padded)
__global__ __launch_bounds__(256) void k_transpose_emb(const float* __restrict__ emb,
                                                       unsigned short* __restrict__ embT){
  __shared__ float tile[32][65];
  int v0 = blockIdx.x * 64, k0 = blockIdx.y * 32;
  int tid = threadIdx.x;
  #pragma unroll
  for (int it = 0; it < 8; ++it){
    int idx = it * 256 + tid;
    int kk = idx >> 6, vv = idx & 63;
    int k = k0 + kk, v = v0 + vv;
    float val = 0.f;
    if (k < WD_ && v < V_) val = emb[(size_t)k * V_ + v];
    tile[kk][vv] = val;
  }
  __syncthreads();
  int row = tid >> 2, c = tid & 3;
  unsigned short e[8];
  #pragma unroll
  for (int i = 0; i < 8; ++i) e[i] = f2bf(tile[c*8 + i][row]);
  uint4 pk;
  pk.x = (unsigned)e[0] | ((unsigned)e[1] << 16);
  pk.y = (unsigned)e[2] | ((unsigned)e[3] << 16);
  pk.z = (unsigned)e[4] | ((unsigned)e[5] << 16);
  pk.w = (unsigned)e[6] | ((unsigned)e[7] << 16);
  *(uint4*)&embT[(size_t)(v0 + row) * KP + k0 + c*8] = pk;
}

// ---------------- K0b: diags [2100][300] f32 -> bf16 [MB2][KP] zero-padded
__global__ __launch_bounds__(256) void k_conv_diags(const float* __restrict__ diags,
                                                    unsigned short* __restrict__ diagsB){
  int gid = blockIdx.x * 256 + threadIdx.x;
  int m = gid / 80;
  int k4 = (gid % 80) * 4;
  unsigned short e[4];
  #pragma unroll
  for (int i = 0; i < 4; ++i){
    int k = k4 + i;
    float v = (m < 2100 && k < WD_) ? diags[m * WD_ + k] : 0.f;
    e[i] = f2bf(v);
  }
  uint2 pk;
  pk.x = (unsigned)e[0] | ((unsigned)e[1] << 16);
  pk.y = (unsigned)e[2] | ((unsigned)e[3] << 16);
  *(uint2*)&diagsB[(size_t)m * KP + k4] = pk;
}

// ---------------- vocab compaction ----------------
__global__ __launch_bounds__(256) void k_zero(int* __restrict__ used, int* __restrict__ counter){
  int i = blockIdx.x * 256 + threadIdx.x;
  if (i < NPAD2) used[i] = 0;
  if (i == 0) *counter = 0;
}
__global__ __launch_bounds__(256) void k_mark(const int* __restrict__ docs,
                                              const int* __restrict__ dlens,
                                              int* __restrict__ used){
  int i = blockIdx.x * 256 + threadIdx.x;   // 0..65535
  int b = i >> 11, t = i & 2047;
  if (t < dlens[b]) used[docs[i]] = 1;
}
__global__ __launch_bounds__(256) void k_compact(const int* __restrict__ used,
                                                 int* __restrict__ remap,
                                                 int* __restrict__ inv,
                                                 int* __restrict__ counter){
  int v = blockIdx.x * 256 + threadIdx.x;
  if (v >= V_) return;
  if (used[v]){
    int id = atomicAdd(counter, 1);
    remap[v] = id;
    inv[id] = v;
  }
}
__global__ __launch_bounds__(256) void k_docsC(const int* __restrict__ docs,
                                               const int* __restrict__ dlens,
                                               const int* __restrict__ remap,
                                               int* __restrict__ docsC){
  int i = blockIdx.x * 256 + threadIdx.x;
  int b = i >> 11, t = i & 2047;
  docsC[i] = (t < dlens[b]) ? remap[docs[i]] : 0;
}

// ---------------- K1: trans[id][m] = sum_k embT[inv[id]][k]*diagsB[m][k] + bias[m], bf16 out
// 128x128 tile, 4 waves, BK=32, dbuf LDS, counted vmcnt(4), pre-swizzled source slot.
// vt-inner identity mapping: active blocks (vt*128 < nused) spread uniformly over the
// grid -> balanced across XCDs regardless of nused (round-7 fix: chunked XCD swizzle
// piled all active blocks onto XCDs 0-3).
__global__ __launch_bounds__(256, 4) void k_gemm(const unsigned short* __restrict__ embT,
                                                 const unsigned short* __restrict__ diagsB,
                                                 const float* __restrict__ bias,
                                                 const int* __restrict__ inv,
                                                 const int* __restrict__ nusedp,
                                                 unsigned short* __restrict__ trans){
  __shared__ char smem[33792];   // 2 x (A 8K + B 8K) = 32K; epilogue bf16 [128][132]
  int nused = *nusedp;
  int wg = blockIdx.x;
  int vt = wg % VT_, mt = wg / VT_;
  int v0 = vt * 128, m0 = mt * 128;
  if (v0 >= nused) return;

  int tid = threadIdx.x;
  int w = tid >> 6, l = tid & 63;
  int wv = w & 1, wm = w >> 1;
  int lrow = l & 15, lq = l >> 4;

  // A-row gather indices for this thread's two staged rows
  int rA0 = tid >> 2, rA1 = 64 + (tid >> 2);
  size_t ga0 = (size_t)((v0 + rA0 < nused) ? inv[v0 + rA0] : 0) * KP;
  size_t ga1 = (size_t)((v0 + rA1 < nused) ? inv[v0 + rA1] : 0) * KP;

  f32x4 acc[4][4];
  #pragma unroll
  for (int i = 0; i < 4; ++i)
    #pragma unroll
    for (int j = 0; j < 4; ++j)
      acc[i][j] = (f32x4){0.f, 0.f, 0.f, 0.f};

  auto STAGE = [&](int buf, int kt){
    int k0 = kt * 32;
    char* bA = smem + buf * 16384;
    char* bB = bA + 8192;
    int slot = tid & 3;
    {
      int idx = tid;
      int sc = slot ^ ((rA0 >> 1) & 3);
      GLOAD_LDS16(&embT[ga0 + k0 + sc * 8], bA + idx * 16);
      int row = idx >> 2;
      int scB = slot ^ ((row >> 1) & 3);
      GLOAD_LDS16(&diagsB[(size_t)(m0 + row) * KP + k0 + scB * 8], bB + idx * 16);
    }
    {
      int idx = 256 + tid;
      int sc = slot ^ ((rA1 >> 1) & 3);
      GLOAD_LDS16(&embT[ga1 + k0 + sc * 8], bA + idx * 16);
      int row = idx >> 2;
      int scB = slot ^ ((row >> 1) & 3);
      GLOAD_LDS16(&diagsB[(size_t)(m0 + row) * KP + k0 + scB * 8], bB + idx * 16);
    }
  };

  STAGE(0, 0);
  #pragma unroll
  for (int kt = 0; kt < 10; ++kt){
    if (kt < 9){
      STAGE((kt + 1) & 1, kt + 1);
      asm volatile("s_waitcnt vmcnt(4)" ::: "memory");
    } else {
      asm volatile("s_waitcnt vmcnt(0)" ::: "memory");
    }
    __builtin_amdgcn_s_barrier();
    __builtin_amdgcn_sched_barrier(0);
    char* bA = smem + (kt & 1) * 16384;
    char* bB = bA + 8192;
    bf16x8 af[4], bg[4];
    #pragma unroll
    for (int i = 0; i < 4; ++i){
      int row = wv * 64 + i * 16 + lrow;
      af[i] = *(const bf16x8*)(bA + row * 64 + (lq ^ ((row >> 1) & 3)) * 16);
    }
    #pragma unroll
    for (int j = 0; j < 4; ++j){
      int row = wm * 64 + j * 16 + lrow;
      bg[j] = *(const bf16x8*)(bB + row * 64 + (lq ^ ((row >> 1) & 3)) * 16);
    }
    #pragma unroll
    for (int i = 0; i < 4; ++i)
      #pragma unroll
      for (int j = 0; j < 4; ++j)
        acc[i][j] = __builtin_amdgcn_mfma_f32_16x16x32_bf16(af[i], bg[j], acc[i][j], 0, 0, 0);
    __builtin_amdgcn_sched_barrier(0);
    __builtin_amdgcn_s_barrier();
  }

  // bias per thread's 4 col-groups
  float bv4[4];
  #pragma unroll
  for (int j = 0; j < 4; ++j){
    int mg = m0 + wm * 64 + j * 16 + lrow;
    bv4[j] = (mg < 2100) ? bias[mg] : 0.f;
  }
  // epilogue: regs -> bf16 LDS [128][132] -> coalesced uint2 stores
  unsigned short* eb = (unsigned short*)smem;
  #pragma unroll
  for (int i = 0; i < 4; ++i)
    #pragma unroll
    for (int j = 0; j < 4; ++j)
      #pragma unroll
      for (int r = 0; r < 4; ++r){
        int row = wv * 64 + i * 16 + lq * 4 + r;
        int col = wm * 64 + j * 16 + lrow;
        eb[row * 132 + col] = f2bf(acc[i][j][r] + bv4[j]);
      }
  __syncthreads();
  #pragma unroll
  for (int it = 0; it < 16; ++it){
    int idx2 = it * 256 + tid;
    int row = idx2 >> 5, chq = idx2 & 31;   // chq: 8-byte units (4 bf16)
    int vg = v0 + row, mg = m0 + chq * 4;
    if (vg < nused && mg < MP){
      uint2 val = *(const uint2*)(smem + row * 264 + chq * 8);
      *(uint2*)&trans[(size_t)vg * MP + mg] = val;
    }
  }
}

// ---------------- K3: chunked affine max-plus scan (templated chunk size)
template<int CH>
__global__ __launch_bounds__(192) void k_scan(const unsigned short* __restrict__ trans,
                                              const int* __restrict__ docsC,
                                              const int* __restrict__ doc_lens,
                                              const float* __restrict__ epsilon,
                                              float* __restrict__ chunkout){
  constexpr int NCHT = T_ / CH;
  __shared__ int sdocs[CH];
  int b = blockIdx.x / NCHT, ch = blockIdx.x % NCHT;
  int doclen = doc_lens[b];
  int tbase = ch * CH;
  if (tbase >= doclen) return;   // fully inactive chunk: combine skips it
  int tid = threadIdx.x;
  if (tid < CH) sdocs[tid] = docsC[b * T_ + tbase + tid];
  __syncthreads();
  int p = tid;
  if (p >= P_) return;
  float eps_r[6];
  #pragma unroll
  for (int i = 0; i < 6; ++i) eps_r[i] = epsilon[p*6 + i];
  int endsel = p / 50;

  float col[7][7], bvec[7], uvec[7], w;
  #pragma unroll
  for (int j = 0; j < 7; ++j)
    #pragma unroll
    for (int l = 0; l < 7; ++l) col[j][l] = (j == l) ? 0.f : NEGC;
  #pragma unroll
  for (int l = 0; l < 7; ++l){ bvec[l] = NEGC; uvec[l] = NEGC; }
  w = NEGC;

  const char* transB = (const char*)trans;

  auto LOADQ = [&](unsigned* q, int s){
    int idx = s < CH - 1 ? s : CH - 1;
    const unsigned* rp = (const unsigned*)(transB + (size_t)sdocs[idx] * (MP*2) + p*28);
    #pragma unroll
    for (int i = 0; i < 7; ++i) q[i] = rp[i];
  };

  auto step = [&](const unsigned* q, bool act){
    float tsf[7], tmn[6];
    tsf[0]=bf_lo(q[0]); tsf[1]=bf_hi(q[0]);
    tsf[2]=bf_lo(q[1]); tsf[3]=bf_hi(q[1]);
    tsf[4]=bf_lo(q[2]); tsf[5]=bf_hi(q[2]);
    tsf[6]=bf_lo(q[3]); tmn[0]=bf_hi(q[3]);
    tmn[1]=bf_lo(q[4]); tmn[2]=bf_hi(q[4]);
    tmn[3]=bf_lo(q[5]); tmn[4]=bf_hi(q[5]);
    tmn[5]=bf_lo(q[6]);
    #pragma unroll
    for (int j = 0; j < 7; ++j){
      #pragma unroll
      for (int l = 6; l >= 1; --l){
        if (l < j) continue;
        if (l == j){ col[j][l] = col[j][l] + tsf[l]; continue; }
        float ae;
        if (l - 1 == j) ae = col[j][l-1];
        else ae = fmaxf(col[j][l-1], col[j][l-2] + eps_r[l-2]);
        col[j][l] = fmaxf(ae + tmn[l-1], col[j][l] + tsf[l]);
      }
      if (j == 0) col[0][0] += tsf[0];
    }
    #pragma unroll
    for (int l = 6; l >= 1; --l){
      float ae;
      if (l == 1) ae = fmaxf(bvec[0], -100.0f);
      else ae = fmaxf(bvec[l-1], bvec[l-2] + eps_r[l-2]);
      bvec[l] = fmaxf(ae + tmn[l-1], bvec[l] + tsf[l]);
    }
    bvec[0] = fmaxf(0.0f, bvec[0] + tsf[0]);
    if (act){
      #pragma unroll
      for (int j = 0; j < 7; ++j){
        float c4 = (j <= 4) ? col[j][4] : NEGC;
        float c5 = (j <= 5) ? col[j][5] : NEGC;
        float c6 = col[j][6];
        float ce = (endsel == 0) ? c4 : ((endsel == 1) ? c5 : c6);
        uvec[j] = fmaxf(uvec[j], ce);
      }
      float be = (endsel == 0) ? bvec[4] : ((endsel == 1) ? bvec[5] : bvec[6]);
      w = fmaxf(w, be);
    }
  };

  unsigned q0[7], q1[7], q2[7], q3[7];
  LOADQ(q0, 0); LOADQ(q1, 1); LOADQ(q2, 2);
  for (int s = 0; s < CH; s += 4){
    LOADQ(q3, s + 3); step(q0, (tbase + s)     < doclen);
    LOADQ(q0, s + 4); step(q1, (tbase + s + 1) < doclen);
    LOADQ(q1, s + 5); step(q2, (tbase + s + 2) < doclen);
    LOADQ(q2, s + 6); step(q3, (tbase + s + 3) < doclen);
  }

  float out[44];
  int idx = 0;
  #pragma unroll
  for (int j = 0; j < 7; ++j)
    #pragma unroll
    for (int l = j; l < 7; ++l) out[idx++] = col[j][l];
  #pragma unroll
  for (int l = 0; l < 7; ++l) out[28 + l] = bvec[l];
  #pragma unroll
  for (int l = 0; l < 7; ++l) out[35 + l] = uvec[l];
  out[42] = w; out[43] = 0.f;
  float* dst = chunkout + ((size_t)(b * NCHT + ch) * P_ + p) * 44;
  #pragma unroll
  for (int i = 0; i < 11; ++i){
    float4 t2 = make_float4(out[4*i], out[4*i+1], out[4*i+2], out[4*i+3]);
    ((float4*)dst)[i] = t2;
  }
}

// ---------------- K45: per-(b,p) fold of active chunks + MLP head
__global__ __launch_bounds__(192) void k_combine_mlp(const float* __restrict__ chunkout,
                                                     const int* __restrict__ doc_lens,
                                                     const float* __restrict__ w0,
                                                     const float* __restrict__ b0,
                                                     const float* __restrict__ w1,
                                                     const float* __restrict__ b1,
                                                     float* __restrict__ out,
                                                     int nch, int chsz){
  __shared__ float ssc[P_];
  __shared__ float sh[100];
  int b = blockIdx.x, tid = threadIdx.x;
  if (tid < P_){
    int p = tid;
    int doclen = doc_lens[b];
    int nact = (doclen + chsz - 1) / chsz;
    if (nact > nch) nact = nch;
    float h[7] = {0.f, -100.f, -100.f, -100.f, -100.f, -100.f, -100.f};
    float sc = -100.f;
    for (int ch = 0; ch < nact; ++ch){
      const float* rec = chunkout + ((size_t)(b * nch + ch) * P_ + p) * 44;
      float r[44];
      #pragma unroll
      for (int i = 0; i < 11; ++i){
        float4 t = ((const float4*)rec)[i];
        r[4*i] = t.x; r[4*i+1] = t.y; r[4*i+2] = t.z; r[4*i+3] = t.w;
      }
      #pragma unroll
      for (int j = 0; j < 7; ++j) sc = fmaxf(sc, r[35 + j] + h[j]);
      sc = fmaxf(sc, r[42]);
      constexpr int off[7] = {0, 7, 13, 18, 22, 25, 27};
      float nh[7];
      #pragma unroll
      for (int l = 0; l < 7; ++l){
        float v = r[28 + l];
        #pragma unroll
        for (int j = 0; j < 7; ++j){
          if (j <= l) v = fmaxf(v, r[off[j] + (l - j)] + h[j]);
        }
        nh[l] = v;
      }
      #pragma unroll
      for (int l = 0; l < 7; ++l) h[l] = nh[l];
    }
    ssc[p] = sc;
  }
  __syncthreads();
  if (tid < 100){
    float a = b0[tid];
    for (int pp = 0; pp < P_; ++pp) a += ssc[pp] * w0[pp * 100 + tid];
    sh[tid] = fmaxf(a, 0.f);
  }
  __syncthreads();
  if (tid < 2){
    float o = b1[tid];
    for (int j = 0; j < 100; ++j) o += sh[j] * w1[j * 2 + tid];
    out[b * 2 + tid] = o;
  }
}

extern "C" void kernel_launch(void* const* d_in, const int* in_sizes, int n_in,
                              void* d_out, int out_size, void* d_ws, size_t ws_size,
                              hipStream_t stream){
  const float* emb   = (const float*)d_in[0];
  const float* diags = (const float*)d_in[1];
  const float* bias  = (const float*)d_in[2];
  const float* eps   = (const float*)d_in[3];
  const float* w0    = (const float*)d_in[4];
  const float* b0    = (const float*)d_in[5];
  const float* w1    = (const float*)d_in[6];
  const float* b1    = (const float*)d_in[7];
  const int* docs    = (const int*)d_in[8];
  const int* dlens   = (const int*)d_in[9];

  if (ws_size < (size_t)WS_NEED_SMALL) return;  // all-zero output => ws too small
  bool big = ws_size >= (size_t)WS_NEED_BIG;

  char* ws = (char*)d_ws;
  unsigned short* embT   = (unsigned short*)(ws);
  unsigned short* diagsB = (unsigned short*)(ws + WS_DIAGSB);
  unsigned short* trans  = (unsigned short*)(ws + (big ? WS_TRANS_BIG : WS_TRANS_SMALL));
  char* aux              = ws + (big ? WS_AUX_BIG : WS_AUX_SMALL);
  int* used    = (int*)(aux);                 // 50176
  int* remap   = (int*)(aux + 200704u);       // 50176
  int* inv     = (int*)(aux + 401408u);       // 50176
  int* docsC   = (int*)(aux + 602112u);       // 65536
  int* counter = (int*)(aux + 864256u);       // 1
  float* chunkout = (float*)(ws);             // aliases embT+diagsB (dead after gemm)
  float* outp = (float*)d_out;

  k_transpose_emb<<<dim3(NPAD2/64, KP/32), 256, 0, stream>>>(emb, embT);
  k_conv_diags<<<(MB2*80 + 255)/256, 256, 0, stream>>>(diags, diagsB);
  k_zero<<<NPAD2/256, 256, 0, stream>>>(used, counter);
  k_mark<<<B_*T_/256, 256, 0, stream>>>(docs, dlens, used);
  k_compact<<<(V_ + 255)/256, 256, 0, stream>>>(used, remap, inv, counter);
  k_docsC<<<B_*T_/256, 256, 0, stream>>>(docs, dlens, remap, docsC);
  k_gemm<<<NWG, 256, 0, stream>>>(embT, diagsB, bias, inv, counter, trans);
  if (big){
    k_scan<32><<<B_ * 64, 192, 0, stream>>>(trans, docsC, dlens, eps, chunkout);
    k_combine_mlp<<<B_, 192, 0, stream>>>(chunkout, dlens, w0, b0, w1, b1, outp, 64, 32);
  } else {
    k_scan<64><<<B_ * 32, 192, 0, stream>>>(trans, docsC, dlens, eps, chunkout);
    k_combine_mlp<<<B_, 192, 0, stream>>>(chunkout, dlens, w0, b0, w1, b1, outp, 32, 64);
  }
}

// Round 9
// 181.702 us; speedup vs baseline: 3.4257x; 1.0837x over previous
//
#include <hip/hip_runtime.h>
#include <stdint.h>

#define B_   32
#define T_   2048
#define V_   50000
#define WD_  300
#define P_   150
#define KP   320       // K padded (300 -> 320)
#define MP   2112      // trans row stride in elements
#define MB2  2176      // diagsB padded rows
#define NPAD2 50176    // V padded (transpose output rows)
#define VT_  391       // max vt with any valid rows (50000/128 -> 391 tiles)
#define MT_  17
#define NWG3 6664      // 8 XCD groups x 49 vt-locals x 17 mt
#define NEGC (-1.0e30f)

// workspace layouts (bytes)
// big (CHUNK=32):  embT@0 (32,112,640) | diagsB@32,112,640 (1,392,640) |
//                  chunkout@0 (54,067,200; aliases embT+diagsB after gemm) |
//                  trans@54,067,200 (211,200,000) | aux@265,267,200 (864,260)
// small (CHUNK=64): trans@33,505,280 | aux@244,705,280; chunkout@0 (27,033,600)
#define WS_DIAGSB      32112640u
#define WS_TRANS_BIG   54067200u
#define WS_TRANS_SMALL 33505280u
#define WS_AUX_BIG     265267200u
#define WS_AUX_SMALL   244705280u
#define AUX_BYTES      864260u
#define WS_NEED_BIG    (WS_AUX_BIG + AUX_BYTES)
#define WS_NEED_SMALL  (WS_AUX_SMALL + AUX_BYTES)

typedef __attribute__((ext_vector_type(8))) short bf16x8;
typedef __attribute__((ext_vector_type(4))) float f32x4;

#define GLOAD_LDS16(gp, lp) __builtin_amdgcn_global_load_lds( \
    (__attribute__((address_space(1))) void*)(gp), \
    (__attribute__((address_space(3))) void*)(lp), 16, 0, 0)

__device__ __forceinline__ unsigned short f2bf(float f){
  unsigned u = __builtin_bit_cast(unsigned, f);
  u = u + 0x7fffu + ((u >> 16) & 1u);   // RNE
  return (unsigned short)(u >> 16);
}
__device__ __forceinline__ float bf_lo(unsigned u){ return __builtin_bit_cast(float, u << 16); }
__device__ __forceinline__ float bf_hi(unsigned u){ return __builtin_bit_cast(float, u & 0xffff0000u); }

// ---------------- K0a: emb [300][50000] f32 -> embT bf16 [NPAD2][KP] (transposed, zero-padded)
__global__ __launch_bounds__(256) void k_transpose_emb(const float* __restrict__ emb,
                                                       unsigned short* __restrict__ embT){
  __shared__ float tile[32][65];
  int v0 = blockIdx.x * 64, k0 = blockIdx.y * 32;
  int tid = threadIdx.x;
  #pragma unroll
  for (int it = 0; it < 8; ++it){
    int idx = it * 256 + tid;
    int kk = idx >> 6, vv = idx & 63;
    int k = k0 + kk, v = v0 + vv;
    float val = 0.f;
    if (k < WD_ && v < V_) val = emb[(size_t)k * V_ + v];
    tile[kk][vv] = val;
  }
  __syncthreads();
  int row = tid >> 2, c = tid & 3;
  unsigned short e[8];
  #pragma unroll
  for (int i = 0; i < 8; ++i) e[i] = f2bf(tile[c*8 + i][row]);
  uint4 pk;
  pk.x = (unsigned)e[0] | ((unsigned)e[1] << 16);
  pk.y = (unsigned)e[2] | ((unsigned)e[3] << 16);
  pk.z = (unsigned)e[4] | ((unsigned)e[5] << 16);
  pk.w = (unsigned)e[6] | ((unsigned)e[7] << 16);
  *(uint4*)&embT[(size_t)(v0 + row) * KP + k0 + c*8] = pk;
}

// ---------------- K0b: diags [2100][300] f32 -> bf16 [MB2][KP] zero-padded
__global__ __launch_bounds__(256) void k_conv_diags(const float* __restrict__ diags,
                                                    unsigned short* __restrict__ diagsB){
  int gid = blockIdx.x * 256 + threadIdx.x;
  int m = gid / 80;
  int k4 = (gid % 80) * 4;
  unsigned short e[4];
  #pragma unroll
  for (int i = 0; i < 4; ++i){
    int k = k4 + i;
    float v = (m < 2100 && k < WD_) ? diags[m * WD_ + k] : 0.f;
    e[i] = f2bf(v);
  }
  uint2 pk;
  pk.x = (unsigned)e[0] | ((unsigned)e[1] << 16);
  pk.y = (unsigned)e[2] | ((unsigned)e[3] << 16);
  *(uint2*)&diagsB[(size_t)m * KP + k4] = pk;
}

// ---------------- vocab compaction ----------------
__global__ __launch_bounds__(256) void k_zero(int* __restrict__ used, int* __restrict__ counter){
  int i = blockIdx.x * 256 + threadIdx.x;
  if (i < NPAD2) used[i] = 0;
  if (i == 0) *counter = 0;
}
__global__ __launch_bounds__(256) void k_mark(const int* __restrict__ docs,
                                              const int* __restrict__ dlens,
                                              int* __restrict__ used){
  int i = blockIdx.x * 256 + threadIdx.x;   // 0..65535
  int b = i >> 11, t = i & 2047;
  if (t < dlens[b]) used[docs[i]] = 1;
}
__global__ __launch_bounds__(256) void k_compact(const int* __restrict__ used,
                                                 int* __restrict__ remap,
                                                 int* __restrict__ inv,
                                                 int* __restrict__ counter){
  int v = blockIdx.x * 256 + threadIdx.x;
  if (v >= V_) return;
  if (used[v]){
    int id = atomicAdd(counter, 1);
    remap[v] = id;
    inv[id] = v;
  }
}
__global__ __launch_bounds__(256) void k_docsC(const int* __restrict__ docs,
                                               const int* __restrict__ dlens,
                                               const int* __restrict__ remap,
                                               int* __restrict__ docsC){
  int i = blockIdx.x * 256 + threadIdx.x;
  int b = i >> 11, t = i & 2047;
  docsC[i] = (t < dlens[b]) ? remap[docs[i]] : 0;
}

// ---------------- K1: trans[id][m] = sum_k embT[inv[id]][k]*diagsB[m][k] + bias[m], bf16 out
// 128x128 tile, 4 waves, BK=32, dbuf LDS, counted vmcnt(4), pre-swizzled source slot.
// Per-XCD vt-strided mapping: xcd = orig&7 owns vts == xcd (mod 8); within an XCD the
// 17 mt blocks of one vt are consecutive -> A-panel fetched once chip-wide, reused in
// that XCD's L2. Active vts spread round-robin -> balanced for any nused.
__global__ __launch_bounds__(256, 4) void k_gemm(const unsigned short* __restrict__ embT,
                                                 const unsigned short* __restrict__ diagsB,
                                                 const float* __restrict__ bias,
                                                 const int* __restrict__ inv,
                                                 const int* __restrict__ nusedp,
                                                 unsigned short* __restrict__ trans){
  __shared__ char smem[33792];   // 2 x (A 8K + B 8K) = 32K; epilogue bf16 [128][132]
  int nused = *nusedp;
  int orig = blockIdx.x;
  int xcd = orig & 7, idx0 = orig >> 3;
  int vt = (idx0 / MT_) * 8 + xcd;
  int mt = idx0 % MT_;
  int v0 = vt * 128, m0 = mt * 128;
  if (v0 >= nused) return;

  int tid = threadIdx.x;
  int w = tid >> 6, l = tid & 63;
  int wv = w & 1, wm = w >> 1;
  int lrow = l & 15, lq = l >> 4;

  // A-row gather indices for this thread's two staged rows
  int rA0 = tid >> 2, rA1 = 64 + (tid >> 2);
  size_t ga0 = (size_t)((v0 + rA0 < nused) ? inv[v0 + rA0] : 0) * KP;
  size_t ga1 = (size_t)((v0 + rA1 < nused) ? inv[v0 + rA1] : 0) * KP;

  f32x4 acc[4][4];
  #pragma unroll
  for (int i = 0; i < 4; ++i)
    #pragma unroll
    for (int j = 0; j < 4; ++j)
      acc[i][j] = (f32x4){0.f, 0.f, 0.f, 0.f};

  auto STAGE = [&](int buf, int kt){
    int k0 = kt * 32;
    char* bA = smem + buf * 16384;
    char* bB = bA + 8192;
    int slot = tid & 3;
    {
      int idx = tid;
      int sc = slot ^ ((rA0 >> 1) & 3);
      GLOAD_LDS16(&embT[ga0 + k0 + sc * 8], bA + idx * 16);
      int row = idx >> 2;
      int scB = slot ^ ((row >> 1) & 3);
      GLOAD_LDS16(&diagsB[(size_t)(m0 + row) * KP + k0 + scB * 8], bB + idx * 16);
    }
    {
      int idx = 256 + tid;
      int sc = slot ^ ((rA1 >> 1) & 3);
      GLOAD_LDS16(&embT[ga1 + k0 + sc * 8], bA + idx * 16);
      int row = idx >> 2;
      int scB = slot ^ ((row >> 1) & 3);
      GLOAD_LDS16(&diagsB[(size_t)(m0 + row) * KP + k0 + scB * 8], bB + idx * 16);
    }
  };

  STAGE(0, 0);
  #pragma unroll
  for (int kt = 0; kt < 10; ++kt){
    if (kt < 9){
      STAGE((kt + 1) & 1, kt + 1);
      asm volatile("s_waitcnt vmcnt(4)" ::: "memory");
    } else {
      asm volatile("s_waitcnt vmcnt(0)" ::: "memory");
    }
    __builtin_amdgcn_s_barrier();
    __builtin_amdgcn_sched_barrier(0);
    char* bA = smem + (kt & 1) * 16384;
    char* bB = bA + 8192;
    bf16x8 af[4], bg[4];
    #pragma unroll
    for (int i = 0; i < 4; ++i){
      int row = wv * 64 + i * 16 + lrow;
      af[i] = *(const bf16x8*)(bA + row * 64 + (lq ^ ((row >> 1) & 3)) * 16);
    }
    #pragma unroll
    for (int j = 0; j < 4; ++j){
      int row = wm * 64 + j * 16 + lrow;
      bg[j] = *(const bf16x8*)(bB + row * 64 + (lq ^ ((row >> 1) & 3)) * 16);
    }
    #pragma unroll
    for (int i = 0; i < 4; ++i)
      #pragma unroll
      for (int j = 0; j < 4; ++j)
        acc[i][j] = __builtin_amdgcn_mfma_f32_16x16x32_bf16(af[i], bg[j], acc[i][j], 0, 0, 0);
    __builtin_amdgcn_sched_barrier(0);
    __builtin_amdgcn_s_barrier();
  }

  // bias per thread's 4 col-groups
  float bv4[4];
  #pragma unroll
  for (int j = 0; j < 4; ++j){
    int mg = m0 + wm * 64 + j * 16 + lrow;
    bv4[j] = (mg < 2100) ? bias[mg] : 0.f;
  }
  // epilogue: regs -> bf16 LDS [128][132] -> coalesced uint2 stores
  unsigned short* eb = (unsigned short*)smem;
  #pragma unroll
  for (int i = 0; i < 4; ++i)
    #pragma unroll
    for (int j = 0; j < 4; ++j)
      #pragma unroll
      for (int r = 0; r < 4; ++r){
        int row = wv * 64 + i * 16 + lq * 4 + r;
        int col = wm * 64 + j * 16 + lrow;
        eb[row * 132 + col] = f2bf(acc[i][j][r] + bv4[j]);
      }
  __syncthreads();
  #pragma unroll
  for (int it = 0; it < 16; ++it){
    int idx2 = it * 256 + tid;
    int row = idx2 >> 5, chq = idx2 & 31;   // chq: 8-byte units (4 bf16)
    int vg = v0 + row, mg = m0 + chq * 4;
    if (vg < nused && mg < MP){
      uint2 val = *(const uint2*)(smem + row * 264 + chq * 8);
      *(uint2*)&trans[(size_t)vg * MP + mg] = val;
    }
  }
}

// ---------------- K3: chunked affine max-plus scan (templated chunk size)
// dual register-set software pipeline (depth 4-8): issue 4 row-loads, run 4 steps.
template<int CH>
__global__ __launch_bounds__(192) void k_scan(const unsigned short* __restrict__ trans,
                                              const int* __restrict__ docsC,
                                              const int* __restrict__ doc_lens,
                                              const float* __restrict__ epsilon,
                                              float* __restrict__ chunkout){
  constexpr int NCHT = T_ / CH;
  __shared__ int sdocs[CH];
  int b = blockIdx.x / NCHT, ch = blockIdx.x % NCHT;
  int doclen = doc_lens[b];
  int tbase = ch * CH;
  if (tbase >= doclen) return;   // fully inactive chunk: combine skips it
  int tid = threadIdx.x;
  if (tid < CH) sdocs[tid] = docsC[b * T_ + tbase + tid];
  __syncthreads();
  int p = tid;
  if (p >= P_) return;
  float eps_r[6];
  #pragma unroll
  for (int i = 0; i < 6; ++i) eps_r[i] = epsilon[p*6 + i];
  int endsel = p / 50;

  float col[7][7], bvec[7], uvec[7], w;
  #pragma unroll
  for (int j = 0; j < 7; ++j)
    #pragma unroll
    for (int l = 0; l < 7; ++l) col[j][l] = (j == l) ? 0.f : NEGC;
  #pragma unroll
  for (int l = 0; l < 7; ++l){ bvec[l] = NEGC; uvec[l] = NEGC; }
  w = NEGC;

  const char* transB = (const char*)trans;

  auto LOADQ = [&](unsigned* q, int s){
    int idx = s < CH - 1 ? s : CH - 1;
    const unsigned* rp = (const unsigned*)(transB + (size_t)sdocs[idx] * (MP*2) + p*28);
    #pragma unroll
    for (int i = 0; i < 7; ++i) q[i] = rp[i];
  };

  auto step = [&](const unsigned* q, bool act){
    float tsf[7], tmn[6];
    tsf[0]=bf_lo(q[0]); tsf[1]=bf_hi(q[0]);
    tsf[2]=bf_lo(q[1]); tsf[3]=bf_hi(q[1]);
    tsf[4]=bf_lo(q[2]); tsf[5]=bf_hi(q[2]);
    tsf[6]=bf_lo(q[3]); tmn[0]=bf_hi(q[3]);
    tmn[1]=bf_lo(q[4]); tmn[2]=bf_hi(q[4]);
    tmn[3]=bf_lo(q[5]); tmn[4]=bf_hi(q[5]);
    tmn[5]=bf_lo(q[6]);
    #pragma unroll
    for (int j = 0; j < 7; ++j){
      #pragma unroll
      for (int l = 6; l >= 1; --l){
        if (l < j) continue;
        if (l == j){ col[j][l] = col[j][l] + tsf[l]; continue; }
        float ae;
        if (l - 1 == j) ae = col[j][l-1];
        else ae = fmaxf(col[j][l-1], col[j][l-2] + eps_r[l-2]);
        col[j][l] = fmaxf(ae + tmn[l-1], col[j][l] + tsf[l]);
      }
      if (j == 0) col[0][0] += tsf[0];
    }
    #pragma unroll
    for (int l = 6; l >= 1; --l){
      float ae;
      if (l == 1) ae = fmaxf(bvec[0], -100.0f);
      else ae = fmaxf(bvec[l-1], bvec[l-2] + eps_r[l-2]);
      bvec[l] = fmaxf(ae + tmn[l-1], bvec[l] + tsf[l]);
    }
    bvec[0] = fmaxf(0.0f, bvec[0] + tsf[0]);
    if (act){
      #pragma unroll
      for (int j = 0; j < 7; ++j){
        float c4 = (j <= 4) ? col[j][4] : NEGC;
        float c5 = (j <= 5) ? col[j][5] : NEGC;
        float c6 = col[j][6];
        float ce = (endsel == 0) ? c4 : ((endsel == 1) ? c5 : c6);
        uvec[j] = fmaxf(uvec[j], ce);
      }
      float be = (endsel == 0) ? bvec[4] : ((endsel == 1) ? bvec[5] : bvec[6]);
      w = fmaxf(w, be);
    }
  };

  unsigned qa0[7], qa1[7], qa2[7], qa3[7];
  unsigned qb0[7], qb1[7], qb2[7], qb3[7];
  LOADQ(qa0, 0); LOADQ(qa1, 1); LOADQ(qa2, 2); LOADQ(qa3, 3);
  for (int s = 0; s < CH; s += 8){
    LOADQ(qb0, s + 4); LOADQ(qb1, s + 5); LOADQ(qb2, s + 6); LOADQ(qb3, s + 7);
    step(qa0, (tbase + s)     < doclen);
    step(qa1, (tbase + s + 1) < doclen);
    step(qa2, (tbase + s + 2) < doclen);
    step(qa3, (tbase + s + 3) < doclen);
    LOADQ(qa0, s + 8); LOADQ(qa1, s + 9); LOADQ(qa2, s + 10); LOADQ(qa3, s + 11);
    step(qb0, (tbase + s + 4) < doclen);
    step(qb1, (tbase + s + 5) < doclen);
    step(qb2, (tbase + s + 6) < doclen);
    step(qb3, (tbase + s + 7) < doclen);
  }

  float out[44];
  int idx = 0;
  #pragma unroll
  for (int j = 0; j < 7; ++j)
    #pragma unroll
    for (int l = j; l < 7; ++l) out[idx++] = col[j][l];
  #pragma unroll
  for (int l = 0; l < 7; ++l) out[28 + l] = bvec[l];
  #pragma unroll
  for (int l = 0; l < 7; ++l) out[35 + l] = uvec[l];
  out[42] = w; out[43] = 0.f;
  float* dst = chunkout + ((size_t)(b * NCHT + ch) * P_ + p) * 44;
  #pragma unroll
  for (int i = 0; i < 11; ++i){
    float4 t2 = make_float4(out[4*i], out[4*i+1], out[4*i+2], out[4*i+3]);
    ((float4*)dst)[i] = t2;
  }
}

// ---------------- K45: per-(b,p) fold of active chunks + MLP head
__global__ __launch_bounds__(192) void k_combine_mlp(const float* __restrict__ chunkout,
                                                     const int* __restrict__ doc_lens,
                                                     const float* __restrict__ w0,
                                                     const float* __restrict__ b0,
                                                     const float* __restrict__ w1,
                                                     const float* __restrict__ b1,
                                                     float* __restrict__ out,
                                                     int nch, int chsz){
  __shared__ float ssc[P_];
  __shared__ float sh[100];
  int b = blockIdx.x, tid = threadIdx.x;
  if (tid < P_){
    int p = tid;
    int doclen = doc_lens[b];
    int nact = (doclen + chsz - 1) / chsz;
    if (nact > nch) nact = nch;
    float h[7] = {0.f, -100.f, -100.f, -100.f, -100.f, -100.f, -100.f};
    float sc = -100.f;
    for (int ch = 0; ch < nact; ++ch){
      const float* rec = chunkout + ((size_t)(b * nch + ch) * P_ + p) * 44;
      float r[44];
      #pragma unroll
      for (int i = 0; i < 11; ++i){
        float4 t = ((const float4*)rec)[i];
        r[4*i] = t.x; r[4*i+1] = t.y; r[4*i+2] = t.z; r[4*i+3] = t.w;
      }
      #pragma unroll
      for (int j = 0; j < 7; ++j) sc = fmaxf(sc, r[35 + j] + h[j]);
      sc = fmaxf(sc, r[42]);
      constexpr int off[7] = {0, 7, 13, 18, 22, 25, 27};
      float nh[7];
      #pragma unroll
      for (int l = 0; l < 7; ++l){
        float v = r[28 + l];
        #pragma unroll
        for (int j = 0; j < 7; ++j){
          if (j <= l) v = fmaxf(v, r[off[j] + (l - j)] + h[j]);
        }
        nh[l] = v;
      }
      #pragma unroll
      for (int l = 0; l < 7; ++l) h[l] = nh[l];
    }
    ssc[p] = sc;
  }
  __syncthreads();
  if (tid < 100){
    float a = b0[tid];
    for (int pp = 0; pp < P_; ++pp) a += ssc[pp] * w0[pp * 100 + tid];
    sh[tid] = fmaxf(a, 0.f);
  }
  __syncthreads();
  if (tid < 2){
    float o = b1[tid];
    for (int j = 0; j < 100; ++j) o += sh[j] * w1[j * 2 + tid];
    out[b * 2 + tid] = o;
  }
}

extern "C" void kernel_launch(void* const* d_in, const int* in_sizes, int n_in,
                              void* d_out, int out_size, void* d_ws, size_t ws_size,
                              hipStream_t stream){
  const float* emb   = (const float*)d_in[0];
  const float* diags = (const float*)d_in[1];
  const float* bias  = (const float*)d_in[2];
  const float* eps   = (const float*)d_in[3];
  const float* w0    = (const float*)d_in[4];
  const float* b0    = (const float*)d_in[5];
  const float* w1    = (const float*)d_in[6];
  const float* b1    = (const float*)d_in[7];
  const int* docs    = (const int*)d_in[8];
  const int* dlens   = (const int*)d_in[9];

  if (ws_size < (size_t)WS_NEED_SMALL) return;  // all-zero output => ws too small
  bool big = ws_size >= (size_t)WS_NEED_BIG;

  char* ws = (char*)d_ws;
  unsigned short* embT   = (unsigned short*)(ws);
  unsigned short* diagsB = (unsigned short*)(ws + WS_DIAGSB);
  unsigned short* trans  = (unsigned short*)(ws + (big ? WS_TRANS_BIG : WS_TRANS_SMALL));
  char* aux              = ws + (big ? WS_AUX_BIG : WS_AUX_SMALL);
  int* used    = (int*)(aux);                 // 50176
  int* remap   = (int*)(aux + 200704u);       // 50176
  int* inv     = (int*)(aux + 401408u);       // 50176
  int* docsC   = (int*)(aux + 602112u);       // 65536
  int* counter = (int*)(aux + 864256u);       // 1
  float* chunkout = (float*)(ws);             // aliases embT+diagsB (dead after gemm)
  float* outp = (float*)d_out;

  k_transpose_emb<<<dim3(NPAD2/64, KP/32), 256, 0, stream>>>(emb, embT);
  k_conv_diags<<<(MB2*80 + 255)/256, 256, 0, stream>>>(diags, diagsB);
  k_zero<<<NPAD2/256, 256, 0, stream>>>(used, counter);
  k_mark<<<B_*T_/256, 256, 0, stream>>>(docs, dlens, used);
  k_compact<<<(V_ + 255)/256, 256, 0, stream>>>(used, remap, inv, counter);
  k_docsC<<<B_*T_/256, 256, 0, stream>>>(docs, dlens, remap, docsC);
  k_gemm<<<NWG3, 256, 0, stream>>>(embT, diagsB, bias, inv, counter, trans);
  if (big){
    k_scan<32><<<B_ * 64, 192, 0, stream>>>(trans, docsC, dlens, eps, chunkout);
    k_combine_mlp<<<B_, 192, 0, stream>>>(chunkout, dlens, w0, b0, w1, b1, outp, 64, 32);
  } else {
    k_scan<64><<<B_ * 32, 192, 0, stream>>>(trans, docsC, dlens, eps, chunkout);
    k_combine_mlp<<<B_, 192, 0, stream>>>(chunkout, dlens, w0, b0, w1, b1, outp, 32, 64);
  }
}